// Round 8
// baseline (1552.637 us; speedup 1.0000x reference)
//
#include <hip/hip_runtime.h>
#include <math.h>

#define GAIN 1.6778523489932886f     // 1/0.596
#define MPS  1.3130643285972254f     // 1/sqrt(0.7^2+0.3^2)

typedef __attribute__((ext_vector_type(8))) short short8;
typedef __attribute__((ext_vector_type(4))) short short4v;
typedef __attribute__((ext_vector_type(4))) float float4v;

__device__ __forceinline__ float silu_g(float x){
  float s = 1.0f/(1.0f + __expf(-x));
  return x*s*GAIN;
}
__device__ __forceinline__ short f2bf(float f){
  unsigned u = __builtin_bit_cast(unsigned, f);
  u += 0x7fffu + ((u >> 16) & 1u);
  return (short)(u >> 16);
}
__device__ __forceinline__ float bf2f(unsigned short h){
  return __builtin_bit_cast(float, ((unsigned)h) << 16);
}

// ---------------- weight row-norm reciprocals ----------------
struct NormEnt { const float* w; int O, K, off; };
struct NormArgs { NormEnt e[16]; };

__global__ __launch_bounds__(64) void rownorm_kernel(NormArgs na, float* invw){
  int row = blockIdx.x;
  int base = 0; int i;
  for (i = 0; i < 16; i++){
    if (row < base + na.e[i].O) break;
    base += na.e[i].O;
  }
  if (i >= 16) return;
  int r = row - base; int K = na.e[i].K;
  const float* w = na.e[i].w + (long)r*K;
  float s = 0.f;
  for (int k = threadIdx.x; k < K; k += 64){ float v = w[k]; s += v*v; }
  for (int off = 32; off; off >>= 1) s += __shfl_down(s, off);
  if (threadIdx.x == 0) invw[na.e[i].off + r] = rsqrtf(s + 1e-8f);
}

// ---------------- weight cast: bf16(w * invw[row]) ----------------
struct WcEnt { const float* src; int dstOff, K, invwOff, base; };
struct WcArgs { WcEnt e[16]; int total; };

__global__ __launch_bounds__(256) void wcast_kernel(WcArgs a, const float* __restrict__ invw,
                                                    unsigned short* __restrict__ wbf){
  int gid = blockIdx.x*256 + threadIdx.x;
  if (gid >= a.total) return;
  int i = 0;
  #pragma unroll
  for (int t = 1; t < 16; t++) if (gid >= a.e[t].base) i = t;
  int e = gid - a.e[i].base;
  int row = e / a.e[i].K;
  wbf[a.e[i].dstOff + e] = (unsigned short)f2bf(a.e[i].src[e] * invw[a.e[i].invwOff + row]);
}

// ---------------- audio projection stats (one wave) ----------------
__global__ __launch_bounds__(64) void projstats_kernel(const float* __restrict__ pw, const float* __restrict__ pb,
                                                       float* __restrict__ S){
  int t = threadIdx.x;
  float p = pw[t], q = pb[t];
  float s1 = p*p, s2 = p*q, s3 = q*q;
  for (int off = 32; off; off >>= 1){
    s1 += __shfl_down(s1, off); s2 += __shfl_down(s2, off); s3 += __shfl_down(s3, off);
  }
  if (t == 0){ S[0] = s1; S[1] = s2; S[2] = s3; }
}

// ---------------- b0 inverse pixel-norm (closed form, element-wise 4-wide) ----------------
__global__ __launch_bounds__(256) void invn_audio_kernel(const float* __restrict__ audio, const float* __restrict__ S,
                                                         float* __restrict__ invn){
  long i = blockIdx.x*256 + threadIdx.x;
  if (i >= (2L*128*2048)/4) return;
  long e = i*4;
  float S1 = S[0], S2 = S[1], S3 = S[2];
  float4v a = *(const float4v*)&audio[e];
  float4v o;
  #pragma unroll
  for (int j = 0; j < 4; j++) o[j] = rsqrtf((a[j]*a[j]*S1 + 2.f*a[j]*S2 + S3)/64.f + 1e-4f);
  *(float4v*)&invn[e] = o;
}

// ---------------- pixel-norm reduce (fp32 or bf16 source) ----------------
template<int G, bool BF>
__global__ __launch_bounds__(256) void invn_reduce_kernel(const void* __restrict__ Xv, float* __restrict__ invn,
                                                          int C, int F){
  constexpr int L = 256/G;
  int t = threadIdx.x; int cs = t / L; int li = t % L;
  long pos = (long)blockIdx.x*L + li;
  int bf = (int)(pos >> 11); int l = (int)(pos & 2047);
  int b = bf / F; int f = bf - b*F;
  long base = ((long)b*C*F + f)*2048 + l;
  long stride = (long)F*2048;
  float s = 0.f;
  if (BF){
    const unsigned short* X = (const unsigned short*)Xv;
    for (int c = cs; c < C; c += G){ float v = bf2f(X[base + (long)c*stride]); s += v*v; }
  } else {
    const float* X = (const float*)Xv;
    for (int c = cs; c < C; c += G){ float v = X[base + (long)c*stride]; s += v*v; }
  }
  __shared__ float red[256];
  red[t] = s; __syncthreads();
  #pragma unroll
  for (int off = G/2; off > 0; off >>= 1){
    if (cs < off) red[t] += red[t + off*L];
    __syncthreads();
  }
  if (cs == 0) invn[pos] = rsqrtf(red[li]/(float)C + 1e-4f);
}

// ---------------- pixel-norm apply (fp32 or bf16 source) ----------------
template<bool SILU, bool BF>
__global__ __launch_bounds__(256) void applynorm_kernel(const void* __restrict__ Xv, const float* __restrict__ invn,
                                                        unsigned short* __restrict__ XB, int C, int F, long total4){
  long i = blockIdx.x*256 + threadIdx.x;
  if (i >= total4) return;
  long e = i*4;
  int l = (int)(e & 2047); long r = e >> 11;      // r = (b*C + c)*F + f
  int f = (int)(r % F); long bc = r / F; int b = (int)(bc / C);
  float4v x;
  if (BF){
    short4v u = *(const short4v*)((const unsigned short*)Xv + e);
    x = (float4v){ bf2f((unsigned short)u[0]), bf2f((unsigned short)u[1]),
                   bf2f((unsigned short)u[2]), bf2f((unsigned short)u[3]) };
  } else {
    x = *(const float4v*)((const float*)Xv + e);
  }
  float4v iv = *(const float4v*)&invn[((long)b*F + f)*2048 + l];
  short4v o;
  #pragma unroll
  for (int j = 0; j < 4; j++){
    float v = x[j]*iv[j];
    o[j] = f2bf(SILU ? silu_g(v) : v);
  }
  *(short4v*)&XB[e] = o;
}

// ---------------- freq-pool: P[b,k,f2,l] = mean_p Hb[b,k,f2*s+p,l], bf16 ----------------
__global__ __launch_bounds__(256) void poolf_kernel(const unsigned short* __restrict__ Hb,
                                                    unsigned short* __restrict__ P,
                                                    int F2, int s, int Lc, long total4){
  long i = blockIdx.x*256 + threadIdx.x;
  if (i >= total4) return;
  long e = i*4;
  int li = (int)(e % Lc); long r0 = e / Lc;
  int f2 = (int)(r0 % F2); long r = r0 / F2;        // r = b*Kc + k
  const unsigned short* src = Hb + ((long)r*F2*s + (long)f2*s)*Lc + li;
  float a0=0,a1=0,a2=0,a3=0;
  for (int p = 0; p < s; p++){
    short4v u = *(const short4v*)(src + (long)p*Lc);
    a0 += bf2f((unsigned short)u[0]); a1 += bf2f((unsigned short)u[1]);
    a2 += bf2f((unsigned short)u[2]); a3 += bf2f((unsigned short)u[3]);
  }
  float inv = 1.f/(float)s;
  short4v o = { f2bf(a0*inv), f2bf(a1*inv), f2bf(a2*inv), f2bf(a3*inv) };
  *(short4v*)&P[((long)r*F2 + f2)*Lc + li] = o;
}

// ---------------- bf16 MFMA fused GEMM (128x128 tile, register-prefetched K-loop) ----------------
// BMODE: 0 = bf16 copy (windowed/zero-padded), 2 = audio closed-form (b0 conv1)
// EMODE: 1 bf16 store, 2 mp_add auxXH(bf16)->bf16, 3 mp_add audio-proj->bf16
struct GemmArgs {
  const unsigned short* A;       // pre-normalized bf16 weights, row-major K
  const unsigned short* Bh;      // bf16 B source
  const float* invn; const float* audio;
  const float* pw; const float* pb;
  const unsigned short* auxXH;
  unsigned short* CoutH;
  int N, K, Fdim, Lw, lq0, BLw, Bl0, CLw, Cl0, Nsto, Fsrc;
};

template<int BMODE, int EMODE>
__global__ __launch_bounds__(256,2) void mgemm_kernel(GemmArgs g){
  __shared__ __align__(16) unsigned short Asm[128*40];
  __shared__ __align__(16) unsigned short Bsm[128*40];
  const int t = threadIdx.x;
  const int lane = t & 63;
  const int wave = t >> 6;
  const int wc = wave >> 1, wsd = wave & 1;
  const int q = lane >> 4, r16 = lane & 15;
  const int s0 = blockIdx.x * 128;
  const int n0 = blockIdx.y * 128;
  const int FL = g.Fdim * g.Lw;

  // A staging mapping
  const int ar = t >> 1, ah = t & 1;
  const int an = n0 + ar;
  const bool aval = an < g.N;
  const unsigned short* Aptr = g.A + (long)an*g.K + ah*16;

  // B staging mapping: (k-group kg 0..7 of 4k, m-group mg 0..31 of 4m)
  const int kg = t & 7, mg = t >> 3;
  const int mb = s0 + mg*4;
  int bcol = mb / FL; int rr = mb - bcol*FL;
  int fcol = (g.Fdim > 1) ? (rr / g.Lw) : 0;
  int labs = g.lq0 + (rr - fcol*g.Lw);
  const bool cv = (bcol < 2);
  bool lv[4];
  #pragma unroll
  for (int j = 0; j < 4; j++) lv[j] = cv && (labs + j >= 0) && (labs + j < 2048);
  const bool vec4 = cv && (labs >= 0) && (labs + 3 < 2048);
  const unsigned short* bbase = g.Bh;
  if (cv) bbase = g.Bh + ((long)(bcol*g.K)*g.Fsrc + fcol)*g.BLw + (labs - g.Bl0);
  const long kstep = (long)g.Fsrc * g.BLw;

  float invn4[4] = {0,0,0,0}, aud4[4] = {0,0,0,0};
  if (BMODE == 2){
    #pragma unroll
    for (int j = 0; j < 4; j++) if (lv[j]){
      invn4[j] = g.invn[(bcol*g.Fdim + fcol)*2048 + labs + j];
      aud4[j]  = g.audio[(bcol*128 + fcol)*2048 + labs + j];
    }
  }

  float4v acc[4][4];
  #pragma unroll
  for (int i = 0; i < 4; i++)
    #pragma unroll
    for (int j = 0; j < 4; j++) acc[i][j] = (float4v){0.f,0.f,0.f,0.f};

  // prefetch registers
  short8 pa0 = {0,0,0,0,0,0,0,0}, pa1 = {0,0,0,0,0,0,0,0};
  short4v praw[4];
  #pragma unroll
  for (int i = 0; i < 4; i++) praw[i] = (short4v){0,0,0,0};

  auto ldA = [&](int kb){
    if (aval){
      pa0 = *(const short8*)(Aptr + kb);
      pa1 = *(const short8*)(Aptr + kb + 8);
    }
  };
  auto ldB = [&](int kb){
    #pragma unroll
    for (int i = 0; i < 4; i++){
      const int k = kb + kg*4 + i;
      const unsigned short* bp = bbase + (long)k*kstep;
      if (vec4) praw[i] = *(const short4v*)bp;
      else {
        short4v u = {0,0,0,0};
        #pragma unroll
        for (int j = 0; j < 4; j++) if (lv[j]) u[j] = (short)bp[j];
        praw[i] = u;
      }
    }
  };

  ldA(0);
  if (BMODE == 0) ldB(0);

  for (int k0 = 0; k0 < g.K; k0 += 32){
    short8 sa0 = pa0, sa1 = pa1;
    short4v bpk[4];
    if (BMODE == 0){
      #pragma unroll
      for (int j = 0; j < 4; j++){
        short4v p;
        #pragma unroll
        for (int i = 0; i < 4; i++) p[i] = praw[i][j];
        bpk[j] = p;
      }
    } else { // BMODE == 2
      float tv[4][4];
      #pragma unroll
      for (int i = 0; i < 4; i++){
        const int k = k0 + kg*4 + i;
        const float pwk = g.pw[k], pbk = g.pb[k];
        #pragma unroll
        for (int j = 0; j < 4; j++) tv[i][j] = lv[j] ? silu_g((aud4[j]*pwk + pbk)*invn4[j]) : 0.f;
      }
      #pragma unroll
      for (int j = 0; j < 4; j++){
        short4v p;
        #pragma unroll
        for (int i = 0; i < 4; i++) p[i] = f2bf(tv[i][j]);
        bpk[j] = p;
      }
    }
    if (k0 + 32 < g.K){
      ldA(k0 + 32);
      if (BMODE == 0) ldB(k0 + 32);
    }

    __syncthreads();
    *(short8*)&Asm[ar*40 + ah*16]     = sa0;
    *(short8*)&Asm[ar*40 + ah*16 + 8] = sa1;
    #pragma unroll
    for (int j = 0; j < 4; j++)
      *(short4v*)&Bsm[(mg*4 + j)*40 + kg*4] = bpk[j];
    __syncthreads();

    short8 afr[4], bfr[4];
    #pragma unroll
    for (int i = 0; i < 4; i++) afr[i] = *(const short8*)&Asm[(wc*64 + i*16 + r16)*40 + q*8];
    #pragma unroll
    for (int j = 0; j < 4; j++) bfr[j] = *(const short8*)&Bsm[(wsd*64 + j*16 + r16)*40 + q*8];
    #pragma unroll
    for (int i = 0; i < 4; i++)
      #pragma unroll
      for (int j = 0; j < 4; j++)
        acc[i][j] = __builtin_amdgcn_mfma_f32_16x16x32_bf16(afr[i], bfr[j], acc[i][j], 0, 0, 0);
  }

  // ---- epilogue ----
  #pragma unroll
  for (int j = 0; j < 4; j++){
    int sg = s0 + wsd*64 + j*16 + r16;
    int b2 = sg / FL; int r2 = sg - b2*FL;
    int f2 = (g.Fdim > 1) ? (r2 / g.Lw) : 0;
    int l2 = g.lq0 + (r2 - f2*g.Lw);
    if (b2 >= 2 || l2 < 0 || l2 >= 2048) continue;
    float invn_p = 0.f, aud_p = 0.f;
    if (EMODE==2 || EMODE==3) invn_p = g.invn[(b2*g.Fdim + f2)*2048 + l2];
    if (EMODE==3) aud_p = g.audio[(b2*128 + f2)*2048 + l2];
    #pragma unroll
    for (int i = 0; i < 4; i++){
      #pragma unroll
      for (int rg = 0; rg < 4; rg++){
        int n = n0 + wc*64 + i*16 + q*4 + rg;
        if (n >= g.N) continue;
        float v = acc[i][j][rg];
        long oidx = ((long)(b2*g.Nsto + n)*g.Fdim + f2)*g.CLw + (l2 - g.Cl0);
        if (EMODE == 1){
          g.CoutH[oidx] = (unsigned short)f2bf(v);
        } else if (EMODE == 2){
          float xn = bf2f(g.auxXH[((long)(b2*g.N + n)*g.Fdim + f2)*2048 + l2]) * invn_p;
          g.CoutH[oidx] = (unsigned short)f2bf((xn*0.7f + v*0.3f)*MPS);
        } else if (EMODE == 3){
          float xn = (aud_p*g.pw[n] + g.pb[n])*invn_p;
          g.CoutH[oidx] = (unsigned short)f2bf((xn*0.7f + v*0.3f)*MPS);
        }
      }
    }
  }
}

// ---------------- downsample conv GEMM: 64x64 tile on pooled P, prefetched ----------------
// EMODE 0: f32 store full-L ; EMODE 1: bf16 store full-L
struct DnArgs {
  const unsigned short* A; const unsigned short* P;
  float* Cout; unsigned short* CoutH;
  int N, K, F2, Lc, l0;
};

template<int EMODE>
__global__ __launch_bounds__(256,4) void mgemm64_kernel(DnArgs g){
  __shared__ __align__(16) unsigned short Asm[64*40];
  __shared__ __align__(16) unsigned short Bsm[64*40];
  const int t = threadIdx.x;
  const int lane = t & 63;
  const int wave = t >> 6;
  const int wc = wave >> 1, wsd = wave & 1;
  const int q = lane >> 4, r16 = lane & 15;
  const int s0 = blockIdx.x * 64;
  const int n0 = blockIdx.y * 64;
  const int FL = g.F2 * g.Lc;

  const int ar = t >> 2, ah = t & 3;
  const unsigned short* Aptr = g.A + (long)(n0 + ar)*g.K + ah*8;
  const int kg = t & 7, mg = t >> 3;
  const bool bstage = (mg < 16);
  const int mb = s0 + (mg & 15)*4;
  const int bcol = mb / FL; const int rr = mb - bcol*FL;
  const int fcol = rr / g.Lc; const int li = rr - fcol*g.Lc;
  const unsigned short* bbase = g.P + ((long)(bcol*g.K)*g.F2 + fcol)*g.Lc + li;
  const long kstep = (long)g.F2 * g.Lc;

  float4v acc[2][2];
  #pragma unroll
  for (int i = 0; i < 2; i++)
    #pragma unroll
    for (int j = 0; j < 2; j++) acc[i][j] = (float4v){0.f,0.f,0.f,0.f};

  short8 pa = {0,0,0,0,0,0,0,0};
  short4v praw[4];
  #pragma unroll
  for (int i = 0; i < 4; i++) praw[i] = (short4v){0,0,0,0};

  auto ldA = [&](int kb){ pa = *(const short8*)(Aptr + kb); };
  auto ldB = [&](int kb){
    if (bstage){
      #pragma unroll
      for (int i = 0; i < 4; i++)
        praw[i] = *(const short4v*)(bbase + (long)(kb + kg*4 + i)*kstep);
    }
  };
  ldA(0); ldB(0);

  for (int k0 = 0; k0 < g.K; k0 += 32){
    short8 sa = pa;
    short4v bpk[4];
    #pragma unroll
    for (int j = 0; j < 4; j++){
      short4v p;
      #pragma unroll
      for (int i = 0; i < 4; i++) p[i] = praw[i][j];
      bpk[j] = p;
    }
    if (k0 + 32 < g.K){ ldA(k0 + 32); ldB(k0 + 32); }

    __syncthreads();
    *(short8*)&Asm[ar*40 + ah*8] = sa;
    if (bstage){
      #pragma unroll
      for (int j = 0; j < 4; j++)
        *(short4v*)&Bsm[((mg & 15)*4 + j)*40 + kg*4] = bpk[j];
    }
    __syncthreads();

    short8 afr[2], bfr[2];
    #pragma unroll
    for (int i = 0; i < 2; i++) afr[i] = *(const short8*)&Asm[(wc*32 + i*16 + r16)*40 + q*8];
    #pragma unroll
    for (int j = 0; j < 2; j++) bfr[j] = *(const short8*)&Bsm[(wsd*32 + j*16 + r16)*40 + q*8];
    #pragma unroll
    for (int i = 0; i < 2; i++)
      #pragma unroll
      for (int j = 0; j < 2; j++)
        acc[i][j] = __builtin_amdgcn_mfma_f32_16x16x32_bf16(afr[i], bfr[j], acc[i][j], 0, 0, 0);
  }

  #pragma unroll
  for (int j = 0; j < 2; j++){
    int sg = s0 + wsd*32 + j*16 + r16;
    int b2 = sg / FL; int r2 = sg - b2*FL;
    int f2 = r2 / g.Lc; int l2 = g.l0 + (r2 - f2*g.Lc);
    #pragma unroll
    for (int i = 0; i < 2; i++){
      #pragma unroll
      for (int rg = 0; rg < 4; rg++){
        int n = n0 + wc*32 + i*16 + q*4 + rg;
        float v = acc[i][j][rg];
        long oidx = ((long)(b2*g.N + n)*g.F2 + f2)*2048 + l2;
        if (EMODE == 0) g.Cout[oidx] = v;
        else            g.CoutH[oidx] = (unsigned short)f2bf(v);
      }
    }
  }
}

// ---------------- unified seq GEMM: 64x64 tile, Fdim=1, M=4096, prefetched ----------------
// EMODE 1: bf16 store; EMODE 4: split n<Nsto silu->CoutH else raw->Cout2H;
// EMODE 5: mp_add auxX -> f32; EMODE 6: mp_add + silu -> f32
struct SqArgs {
  const unsigned short* A; const unsigned short* Bh;
  const float* invn; const float* auxX;
  float* Cout; unsigned short* CoutH; unsigned short* Cout2H;
  int K, Nsto;
};

template<int EMODE>
__global__ __launch_bounds__(256,4) void seq64_kernel(SqArgs g){
  __shared__ __align__(16) unsigned short Asm[64*40];
  __shared__ __align__(16) unsigned short Bsm[64*40];
  const int t = threadIdx.x;
  const int lane = t & 63;
  const int wave = t >> 6;
  const int wc = wave >> 1, wsd = wave & 1;
  const int q = lane >> 4, r16 = lane & 15;
  const int s0 = blockIdx.x * 64;
  const int n0 = blockIdx.y * 64;
  const int K = g.K;

  const int ar = t >> 2, ah = t & 3;
  const unsigned short* Aptr = g.A + (long)(n0 + ar)*K + ah*8;
  const int kg = t & 7, mg = t >> 3;
  const bool bstage = (mg < 16);
  const int mb = s0 + (mg & 15)*4;
  const int bcol = mb >> 11, lb = mb & 2047;
  const unsigned short* bbase = g.Bh + ((long)bcol*K)*2048 + lb;

  float4v acc[2][2];
  #pragma unroll
  for (int i = 0; i < 2; i++)
    #pragma unroll
    for (int j = 0; j < 2; j++) acc[i][j] = (float4v){0.f,0.f,0.f,0.f};

  short8 pa = {0,0,0,0,0,0,0,0};
  short4v praw[4];
  #pragma unroll
  for (int i = 0; i < 4; i++) praw[i] = (short4v){0,0,0,0};

  auto ldA = [&](int kb){ pa = *(const short8*)(Aptr + kb); };
  auto ldB = [&](int kb){
    if (bstage){
      #pragma unroll
      for (int i = 0; i < 4; i++)
        praw[i] = *(const short4v*)(bbase + (long)(kb + kg*4 + i)*2048);
    }
  };
  ldA(0); ldB(0);

  for (int k0 = 0; k0 < K; k0 += 32){
    short8 sa = pa;
    short4v bpk[4];
    #pragma unroll
    for (int j = 0; j < 4; j++){
      short4v p;
      #pragma unroll
      for (int i = 0; i < 4; i++) p[i] = praw[i][j];
      bpk[j] = p;
    }
    if (k0 + 32 < K){ ldA(k0 + 32); ldB(k0 + 32); }

    __syncthreads();
    *(short8*)&Asm[ar*40 + ah*8] = sa;
    if (bstage){
      #pragma unroll
      for (int j = 0; j < 4; j++)
        *(short4v*)&Bsm[((mg & 15)*4 + j)*40 + kg*4] = bpk[j];
    }
    __syncthreads();

    short8 afr[2], bfr[2];
    #pragma unroll
    for (int i = 0; i < 2; i++) afr[i] = *(const short8*)&Asm[(wc*32 + i*16 + r16)*40 + q*8];
    #pragma unroll
    for (int j = 0; j < 2; j++) bfr[j] = *(const short8*)&Bsm[(wsd*32 + j*16 + r16)*40 + q*8];
    #pragma unroll
    for (int i = 0; i < 2; i++)
      #pragma unroll
      for (int j = 0; j < 2; j++)
        acc[i][j] = __builtin_amdgcn_mfma_f32_16x16x32_bf16(afr[i], bfr[j], acc[i][j], 0, 0, 0);
  }

  #pragma unroll
  for (int j = 0; j < 2; j++){
    int sg = s0 + wsd*32 + j*16 + r16;
    int b2 = sg >> 11, l2 = sg & 2047;
    float invn_p = 0.f;
    if (EMODE == 5 || EMODE == 6) invn_p = g.invn[b2*2048 + l2];
    #pragma unroll
    for (int i = 0; i < 2; i++){
      #pragma unroll
      for (int rg = 0; rg < 4; rg++){
        int n = n0 + wc*32 + i*16 + q*4 + rg;
        float v = acc[i][j][rg];
        if (EMODE == 1){
          g.CoutH[((long)(b2*g.Nsto + n))*2048 + l2] = (unsigned short)f2bf(v);
        } else if (EMODE == 4){
          if (n < g.Nsto) g.CoutH[((long)(b2*g.Nsto + n))*2048 + l2] = (unsigned short)f2bf(silu_g(v));
          else            g.Cout2H[((long)(b2*g.Nsto + (n - g.Nsto)))*2048 + l2] = (unsigned short)f2bf(v);
        } else {
          float xn = g.auxX[((long)b2*512 + n)*2048 + l2] * invn_p;
          float r = (xn*0.7f + v*0.3f)*MPS;
          if (EMODE == 6) r = silu_g(r);
          g.Cout[((long)b2*512 + n)*2048 + l2] = r;
        }
      }
    }
  }
}

// ---------------- depthwise 5x3 conv (+ silu), bf16 in/out ----------------
// 4 f-rows x 8 l per thread; each input row loaded once, feeds up to 3 f-accumulators
struct DwArgs { const unsigned short* R1; const unsigned short* wd; unsigned short* R2; int C, F, Lc, l0; };
__global__ __launch_bounds__(256) void dw2d_kernel(DwArgs a){
  int idx = blockIdx.x*256 + threadIdx.x;
  int Lq = a.Lc >> 3;
  int Fq = a.F >> 2;
  int total = 2*a.C*Fq*Lq;
  if (idx >= total) return;
  int lq = idx % Lq; int r = idx / Lq;
  int fq = r % Fq; r /= Fq;
  int c = r % a.C; int b = r / a.C;
  int f0 = fq*4;
  int labs = a.l0 + lq*8;
  int Lw = a.Lc + 8;
  const unsigned short* base = a.R1 + (long)((b*a.C + c)*a.F)*Lw + (labs - (a.l0 - 4));
  const unsigned short* w = a.wd + c*15;
  float W[5][3];
  #pragma unroll
  for (int tp = 0; tp < 5; tp++)
    #pragma unroll
    for (int j = 0; j < 3; j++) W[tp][j] = bf2f(w[tp*3 + j]);

  const bool llo = (labs > 0);
  const bool lhi = (labs + 8 < 2048);
  float acc[4][8];
  #pragma unroll
  for (int t = 0; t < 4; t++)
    #pragma unroll
    for (int j = 0; j < 8; j++) acc[t][j] = 0.f;

  #pragma unroll
  for (int r8 = 0; r8 < 8; r8++){
    int rrow = f0 - 2 + r8;
    if (rrow < 0 || rrow >= a.F) continue;
    const unsigned short* p = base + (long)rrow*Lw;
    short4v u0 = *(const short4v*)p;
    short4v u1 = *(const short4v*)(p + 4);
    float x[10];
    x[0] = llo ? bf2f(p[-1]) : 0.f;
    x[1] = bf2f((unsigned short)u0[0]); x[2] = bf2f((unsigned short)u0[1]);
    x[3] = bf2f((unsigned short)u0[2]); x[4] = bf2f((unsigned short)u0[3]);
    x[5] = bf2f((unsigned short)u1[0]); x[6] = bf2f((unsigned short)u1[1]);
    x[7] = bf2f((unsigned short)u1[2]); x[8] = bf2f((unsigned short)u1[3]);
    x[9] = lhi ? bf2f(p[8]) : 0.f;
    #pragma unroll
    for (int t = 0; t < 4; t++){
      const int df = r8 - 2 - t;
      if (df < -2 || df > 2) continue;
      float w0 = W[df+2][0], w1 = W[df+2][1], w2 = W[df+2][2];
      #pragma unroll
      for (int j = 0; j < 8; j++)
        acc[t][j] += w0*x[j] + w1*x[j+1] + w2*x[j+2];
    }
  }

  unsigned short* ob = a.R2 + ((long)((b*a.C + c)*a.F + f0))*a.Lc + (labs - a.l0);
  #pragma unroll
  for (int t = 0; t < 4; t++){
    short8 o;
    #pragma unroll
    for (int j = 0; j < 8; j++) o[j] = f2bf(silu_g(acc[t][j]));
    *(short8*)(ob + (long)t*a.Lc) = o;
  }
}

// ---------------- seq depthwise 3-tap (+ silu), bf16 in/out ----------------
__global__ __launch_bounds__(256) void dwseq_kernel(const unsigned short* __restrict__ HS, const unsigned short* __restrict__ w,
                                                    unsigned short* __restrict__ H2){
  int idx = blockIdx.x*256 + threadIdx.x;
  if (idx >= 2*1024*512) return;
  int e = idx*4;
  int tt = e & 2047; int bc = e >> 11; int c = bc & 1023;
  const unsigned short* base = HS + (long)bc*2048 + tt;
  float w0 = bf2f(w[c*3+0]), w1 = bf2f(w[c*3+1]), w2 = bf2f(w[c*3+2]);
  short4v u = *(const short4v*)base;
  float xm = (tt > 0) ? bf2f(base[-1]) : 0.f;
  float x0 = bf2f((unsigned short)u[0]), x1 = bf2f((unsigned short)u[1]);
  float x2 = bf2f((unsigned short)u[2]), x3 = bf2f((unsigned short)u[3]);
  float x4 = (tt < 2044) ? bf2f(base[4]) : 0.f;
  short4v o = { f2bf(silu_g(w0*xm + w1*x0 + w2*x1)),
                f2bf(silu_g(w0*x0 + w1*x1 + w2*x2)),
                f2bf(silu_g(w0*x1 + w1*x2 + w2*x3)),
                f2bf(silu_g(w0*x2 + w1*x3 + w2*x4)) };
  *(short4v*)&H2[(long)bc*2048 + tt] = o;
}

// ---------------- minGRU scan + gate (bf16 z/c) ----------------
__global__ __launch_bounds__(256) void scan_kernel(const unsigned short* __restrict__ ZC, const unsigned short* __restrict__ G,
                                                   unsigned short* __restrict__ SC){
  int bc = blockIdx.x;            // 0..2047 = b*1024+c
  int b = bc >> 10, c = bc & 1023;
  const unsigned short* zrow = ZC + ((long)(b*2048 + c))*2048;
  const unsigned short* crow = ZC + ((long)(b*2048 + 1024 + c))*2048;
  const unsigned short* grow = G + (long)bc*2048;
  unsigned short* orow = SC + (long)bc*2048;
  int tid = threadIdx.x;
  int t0 = tid*8;
  short8 zv = *(const short8*)&zrow[t0];
  short8 cv = *(const short8*)&crow[t0];
  float av[8], bv[8];
  float A = 1.f, Bv = 0.f;
  #pragma unroll
  for (int j = 0; j < 8; j++){
    float z = bf2f((unsigned short)zv[j]); float cval = bf2f((unsigned short)cv[j]);
    float zs = 1.f/(1.f + __expf(-z));
    float a = 1.f - zs; float bb = zs*cval;
    av[j] = a; bv[j] = bb;
    Bv = a*Bv + bb;
    A = a*A;
  }
  __shared__ float sA[256], sB[256];
  sA[tid] = A; sB[tid] = Bv;
  __syncthreads();
  for (int off = 1; off < 256; off <<= 1){
    float pA = 1.f, pB = 0.f;
    if (tid >= off){ pA = sA[tid-off]; pB = sB[tid-off]; }
    __syncthreads();
    float nA = A*pA; float nB = A*pB + Bv;
    A = nA; Bv = nB;
    sA[tid] = A; sB[tid] = Bv;
    __syncthreads();
  }
  float h = (tid > 0) ? sB[tid-1] : 0.f;
  short8 gv = *(const short8*)&grow[t0];
  short8 ov;
  #pragma unroll
  for (int j = 0; j < 8; j++){
    h = av[j]*h + bv[j];
    ov[j] = f2bf(h * silu_g(bf2f((unsigned short)gv[j])));
  }
  *(short8*)&orow[t0] = ov;
}

extern "C" void kernel_launch(void* const* d_in, const int* in_sizes, int n_in,
                              void* d_out, int out_size, void* d_ws, size_t ws_size,
                              hipStream_t stream) {
  const float* audio = (const float*)d_in[0];
  const float* pw = (const float*)d_in[1];
  const float* pb = (const float*)d_in[2];
  const float* cw1[3] = {(const float*)d_in[3], (const float*)d_in[7], (const float*)d_in[11]};
  const float* cwd[3] = {(const float*)d_in[4], (const float*)d_in[8], (const float*)d_in[12]};
  const float* cw2[3] = {(const float*)d_in[5], (const float*)d_in[9], (const float*)d_in[13]};
  const float* cdn[3] = {(const float*)d_in[6], (const float*)d_in[10], (const float*)d_in[14]};
  const float* hgw  = (const float*)d_in[15];
  const float* dww  = (const float*)d_in[16];
  const float* gruw = (const float*)d_in[17];
  const float* outw = (const float*)d_in[18];
  float* out = (float*)d_out;

  // ---- workspace layout (bytes) ----
  char* P0 = (char*)d_ws;
  float*          INVW = (float*)P0;                    P0 += 131072;     // 25664 used + S at [32000]
  unsigned short* WBF  = (unsigned short*)P0;           P0 += 30443776;   // 15,221,888 bf16
  float*          INVN = (float*)P0;                    P0 += 2097152;
  char*           XBZC = P0;                            P0 += 33554432;   // XB (conv b1/b2) / ZC bf16 (seq)
  unsigned short* IN1h = (unsigned short*)P0;           P0 += 33554432;   // b0 out bf16; seq scratch later
  unsigned short* IN2h = (unsigned short*)P0;           P0 += 16777216;   // b1 out bf16
  float*          SEQ  = (float*)P0;                    P0 += 8388608;    // b2 out fp32
  char*           ARENA = P0;
  long arenaBytes = (long)ws_size - (long)(P0 - (char*)d_ws);
  float* S = INVW + 32000;

  // weight table (order: cw1/cwd/cw2/cdn x3, hg, dww, gru, out)
  const float* wsrc[16] = {cw1[0],cwd[0],cw2[0],cdn[0], cw1[1],cwd[1],cw2[1],cdn[1],
                           cw1[2],cwd[2],cw2[2],cdn[2], hgw, dww, gruw, outw};
  int Os[16] = {128,128,64,128, 256,256,128,256, 512,512,256,512, 8192,4096,8192,2048};
  int Ks[16] = {64,15,128,64, 128,15,256,128, 256,15,512,256, 512,3,1024,1024};
  int wbfOff[16], ivOff[16];
  {
    int wo = 0, io = 0;
    for (int i = 0; i < 16; i++){ wbfOff[i] = wo; ivOff[i] = io; wo += Os[i]*Ks[i]; io += Os[i]; }
  }
  {
    NormArgs na;
    int rows = 0;
    for (int i = 0; i < 16; i++){ na.e[i].w = wsrc[i]; na.e[i].O = Os[i]; na.e[i].K = Ks[i]; na.e[i].off = ivOff[i]; rows += Os[i]; }
    rownorm_kernel<<<rows, 64, 0, stream>>>(na, INVW);
  }
  {
    WcArgs wa; int base = 0;
    for (int i = 0; i < 16; i++){
      wa.e[i].src = wsrc[i]; wa.e[i].dstOff = wbfOff[i]; wa.e[i].K = Ks[i];
      wa.e[i].invwOff = ivOff[i]; wa.e[i].base = base; base += Os[i]*Ks[i];
    }
    wa.total = base;
    wcast_kernel<<<(base+255)/256, 256, 0, stream>>>(wa, INVW, WBF);
  }
  projstats_kernel<<<1, 64, 0, stream>>>(pw, pb, S);

  // ---- conv blocks ----
  int Cin_[3]  = {64,128,256};
  int Cmid_[3] = {128,256,512};
  int F_[3]    = {128,32,8};
  int s_[3]    = {4,4,8};
  const unsigned short* XinH[3] = {nullptr, IN1h, IN2h};
  unsigned short* XoutH[3] = {IN1h, IN2h, nullptr};
  int iW1[3]={0,4,8}, iWd[3]={1,5,9}, iW2[3]={2,6,10}, iDn[3]={3,7,11};

  for (int b = 0; b < 3; b++){
    int Cin = Cin_[b], Cmid = Cmid_[b], F = F_[b], s = s_[b];
    int F2 = F/s;
    int nc = 16;
    for (int c = 1; c <= 16; c <<= 1){
      long Lc = 2048/c;
      long bytes = 2L*(2L*Cmid*F*(Lc+8) + 2L*Cmid*F*Lc + 2L*Cin*F*Lc + 2L*Cin*F2*Lc);
      if (bytes <= arenaBytes){ nc = c; break; }
    }
    int Lc = 2048/nc;
    unsigned short* R1 = (unsigned short*)ARENA;
    unsigned short* R2 = R1 + 2L*Cmid*F*(Lc+8);
    unsigned short* Hb = R2 + 2L*Cmid*F*Lc;
    unsigned short* Pb = Hb + 2L*Cin*F*Lc;
    unsigned short* XB = (unsigned short*)XBZC;

    if (b == 0){
      invn_audio_kernel<<<(2*128*2048/4+255)/256, 256, 0, stream>>>(audio, S, INVN);
    } else {
      int positions = 2*F*2048;
      invn_reduce_kernel<8,true><<<positions/32, 256, 0, stream>>>(XinH[b], INVN, Cin, F);
      long total4 = (long)2*Cin*F*2048/4;
      applynorm_kernel<true,true><<<(int)((total4+255)/256), 256, 0, stream>>>(XinH[b], INVN, XB, Cin, F, total4);
    }

    for (int ci = 0; ci < nc; ci++){
      int l0 = ci*Lc;
      // conv1: Cin -> Cmid on window [l0-4, l0+Lc+4) -> R1 bf16
      GemmArgs ga{};
      ga.A = WBF + wbfOff[iW1[b]];
      ga.Bh = XB; ga.invn = INVN; ga.audio = audio; ga.pw = pw; ga.pb = pb;
      ga.CoutH = R1; ga.N = Cmid; ga.K = Cin; ga.Fdim = F; ga.Lw = Lc+8; ga.lq0 = l0-4;
      ga.BLw = 2048; ga.Bl0 = 0; ga.CLw = Lc+8; ga.Cl0 = l0-4; ga.Nsto = Cmid; ga.Fsrc = F;
      int M1 = 2*F*(Lc+8);
      dim3 g1((M1+127)/128, (Cmid+127)/128);
      if (b == 0) mgemm_kernel<2,1><<<g1,256,0,stream>>>(ga);
      else        mgemm_kernel<0,1><<<g1,256,0,stream>>>(ga);
      // depthwise 5x3 + silu -> R2 bf16 (4f x 8l per thread)
      DwArgs da{R1, WBF + wbfOff[iWd[b]], R2, Cmid, F, Lc, l0};
      int tdw = 2*Cmid*(F/4)*(Lc/8);
      dw2d_kernel<<<(tdw+255)/256, 256, 0, stream>>>(da);
      // conv2 + mp_add -> Hb bf16
      GemmArgs gb{};
      gb.A = WBF + wbfOff[iW2[b]];
      gb.Bh = R2; gb.invn = INVN; gb.audio = audio; gb.pw = pw; gb.pb = pb; gb.auxXH = XinH[b];
      gb.CoutH = Hb; gb.N = Cin; gb.K = Cmid; gb.Fdim = F; gb.Lw = Lc; gb.lq0 = l0;
      gb.BLw = Lc; gb.Bl0 = l0; gb.CLw = Lc; gb.Cl0 = l0; gb.Nsto = Cin; gb.Fsrc = F;
      int M2 = 2*F*Lc;
      dim3 g2((M2+127)/128, (Cin+127)/128);
      if (b == 0) mgemm_kernel<0,3><<<g2,256,0,stream>>>(gb);
      else        mgemm_kernel<0,2><<<g2,256,0,stream>>>(gb);
      // freq-pool Hb -> Pb (bf16)
      long tp4 = (2L*Cin*F2*Lc)/4;
      poolf_kernel<<<(int)((tp4+255)/256), 256, 0, stream>>>(Hb, Pb, F2, s, Lc, tp4);
      // dn conv on pooled P -> Xout (bf16 full-L for b0/b1; fp32 SEQ for b2)
      DnArgs dn{};
      dn.A = WBF + wbfOff[iDn[b]]; dn.P = Pb;
      dn.Cout = SEQ; dn.CoutH = XoutH[b];
      dn.N = Cmid; dn.K = Cin; dn.F2 = F2; dn.Lc = Lc; dn.l0 = l0;
      dim3 gdn((2*F2*Lc)/64, Cmid/64);
      if (b == 2) mgemm64_kernel<0><<<gdn,256,0,stream>>>(dn);
      else        mgemm64_kernel<1><<<gdn,256,0,stream>>>(dn);
    }
  }

  // ---- seq blocks (bf16 scratch spans IN1h+IN2h; ZC bf16 in XBZC) ----
  unsigned short* XS = IN1h;
  unsigned short* HS = XS + 2097152;
  unsigned short* G  = HS + 4194304;
  unsigned short* H2 = G  + 4194304;
  unsigned short* SC = H2 + 4194304;
  unsigned short* ZCh = (unsigned short*)XBZC;

  for (int i = 0; i < 4; i++){
    invn_reduce_kernel<16,false><<<4096/16, 256, 0, stream>>>(SEQ, INVN, 512, 1);
    applynorm_kernel<false,false><<<(2*512*2048/4)/256, 256, 0, stream>>>(SEQ, INVN, XS, 512, 1, (long)2*512*2048/4);
    // hg conv (both halves): n<1024 -> silu -> HS, else raw -> G (2048 blocks)
    SqArgs gh{};
    gh.A = WBF + wbfOff[12] + (long)i*2048*512;
    gh.Bh = XS; gh.CoutH = HS; gh.Cout2H = G;
    gh.K = 512; gh.Nsto = 1024;
    seq64_kernel<4><<<dim3(64,32),256,0,stream>>>(gh);
    // depthwise 3-tap + silu
    dwseq_kernel<<<(2*1024*512)/256, 256, 0, stream>>>(HS, WBF + wbfOff[13] + i*1024*3, H2);
    // gru conv 1024 -> 2048 (z|c) -> ZCh bf16 (2048 blocks)
    SqArgs gz{};
    gz.A = WBF + wbfOff[14] + (long)i*2048*1024;
    gz.Bh = H2; gz.CoutH = ZCh;
    gz.K = 1024; gz.Nsto = 2048;
    seq64_kernel<1><<<dim3(64,32),256,0,stream>>>(gz);
    // scan + gate -> SC bf16
    scan_kernel<<<2048,256,0,stream>>>(ZCh, G, SC);
    // out conv + mp_add -> SEQ (i<3) or mp_add+silu -> d_out (i==3)
    SqArgs go{};
    go.A = WBF + wbfOff[15] + (long)i*512*1024;
    go.Bh = SC; go.invn = INVN; go.auxX = SEQ;
    go.K = 1024; go.Nsto = 512;
    if (i < 3){ go.Cout = SEQ; seq64_kernel<5><<<dim3(64,8),256,0,stream>>>(go); }
    else      { go.Cout = out; seq64_kernel<6><<<dim3(64,8),256,0,stream>>>(go); }
  }

  (void)in_sizes; (void)n_in; (void)out_size;
}

// Round 9
// 1525.861 us; speedup vs baseline: 1.0175x; 1.0175x over previous
//
#include <hip/hip_runtime.h>
#include <math.h>

#define GAIN 1.6778523489932886f     // 1/0.596
#define MPS  1.3130643285972254f     // 1/sqrt(0.7^2+0.3^2)

typedef __attribute__((ext_vector_type(8))) short short8;
typedef __attribute__((ext_vector_type(4))) short short4v;
typedef __attribute__((ext_vector_type(4))) float float4v;

__device__ __forceinline__ float silu_g(float x){
  float s = 1.0f/(1.0f + __expf(-x));
  return x*s*GAIN;
}
__device__ __forceinline__ short f2bf(float f){
  unsigned u = __builtin_bit_cast(unsigned, f);
  u += 0x7fffu + ((u >> 16) & 1u);
  return (short)(u >> 16);
}
__device__ __forceinline__ float bf2f(unsigned short h){
  return __builtin_bit_cast(float, ((unsigned)h) << 16);
}

// ---------------- weight row-norm reciprocals ----------------
struct NormEnt { const float* w; int O, K, off; };
struct NormArgs { NormEnt e[16]; };

__global__ __launch_bounds__(64) void rownorm_kernel(NormArgs na, float* invw){
  int row = blockIdx.x;
  int base = 0; int i;
  for (i = 0; i < 16; i++){
    if (row < base + na.e[i].O) break;
    base += na.e[i].O;
  }
  if (i >= 16) return;
  int r = row - base; int K = na.e[i].K;
  const float* w = na.e[i].w + (long)r*K;
  float s = 0.f;
  for (int k = threadIdx.x; k < K; k += 64){ float v = w[k]; s += v*v; }
  for (int off = 32; off; off >>= 1) s += __shfl_down(s, off);
  if (threadIdx.x == 0) invw[na.e[i].off + r] = rsqrtf(s + 1e-8f);
}

// ---------------- weight cast: bf16(w * invw[row]) ----------------
struct WcEnt { const float* src; int dstOff, K, invwOff, base; };
struct WcArgs { WcEnt e[16]; int total; };

__global__ __launch_bounds__(256) void wcast_kernel(WcArgs a, const float* __restrict__ invw,
                                                    unsigned short* __restrict__ wbf){
  int gid = blockIdx.x*256 + threadIdx.x;
  if (gid >= a.total) return;
  int i = 0;
  #pragma unroll
  for (int t = 1; t < 16; t++) if (gid >= a.e[t].base) i = t;
  int e = gid - a.e[i].base;
  int row = e / a.e[i].K;
  wbf[a.e[i].dstOff + e] = (unsigned short)f2bf(a.e[i].src[e] * invw[a.e[i].invwOff + row]);
}

// ---------------- audio projection stats (one wave) ----------------
__global__ __launch_bounds__(64) void projstats_kernel(const float* __restrict__ pw, const float* __restrict__ pb,
                                                       float* __restrict__ S){
  int t = threadIdx.x;
  float p = pw[t], q = pb[t];
  float s1 = p*p, s2 = p*q, s3 = q*q;
  for (int off = 32; off; off >>= 1){
    s1 += __shfl_down(s1, off); s2 += __shfl_down(s2, off); s3 += __shfl_down(s3, off);
  }
  if (t == 0){ S[0] = s1; S[1] = s2; S[2] = s3; }
}

// ---------------- b0 inverse pixel-norm (closed form, element-wise 4-wide) ----------------
__global__ __launch_bounds__(256) void invn_audio_kernel(const float* __restrict__ audio, const float* __restrict__ S,
                                                         float* __restrict__ invn){
  long i = blockIdx.x*256 + threadIdx.x;
  if (i >= (2L*128*2048)/4) return;
  long e = i*4;
  float S1 = S[0], S2 = S[1], S3 = S[2];
  float4v a = *(const float4v*)&audio[e];
  float4v o;
  #pragma unroll
  for (int j = 0; j < 4; j++) o[j] = rsqrtf((a[j]*a[j]*S1 + 2.f*a[j]*S2 + S3)/64.f + 1e-4f);
  *(float4v*)&invn[e] = o;
}

// ---------------- pixel-norm reduce (fp32 or bf16 source) ----------------
template<int G, bool BF>
__global__ __launch_bounds__(256) void invn_reduce_kernel(const void* __restrict__ Xv, float* __restrict__ invn,
                                                          int C, int F){
  constexpr int L = 256/G;
  int t = threadIdx.x; int cs = t / L; int li = t % L;
  long pos = (long)blockIdx.x*L + li;
  int bf = (int)(pos >> 11); int l = (int)(pos & 2047);
  int b = bf / F; int f = bf - b*F;
  long base = ((long)b*C*F + f)*2048 + l;
  long stride = (long)F*2048;
  float s = 0.f;
  if (BF){
    const unsigned short* X = (const unsigned short*)Xv;
    for (int c = cs; c < C; c += G){ float v = bf2f(X[base + (long)c*stride]); s += v*v; }
  } else {
    const float* X = (const float*)Xv;
    for (int c = cs; c < C; c += G){ float v = X[base + (long)c*stride]; s += v*v; }
  }
  __shared__ float red[256];
  red[t] = s; __syncthreads();
  #pragma unroll
  for (int off = G/2; off > 0; off >>= 1){
    if (cs < off) red[t] += red[t + off*L];
    __syncthreads();
  }
  if (cs == 0) invn[pos] = rsqrtf(red[li]/(float)C + 1e-4f);
}

// ---------------- pixel-norm apply (fp32 or bf16 source) ----------------
template<bool SILU, bool BF>
__global__ __launch_bounds__(256) void applynorm_kernel(const void* __restrict__ Xv, const float* __restrict__ invn,
                                                        unsigned short* __restrict__ XB, int C, int F, long total4){
  long i = blockIdx.x*256 + threadIdx.x;
  if (i >= total4) return;
  long e = i*4;
  int l = (int)(e & 2047); long r = e >> 11;      // r = (b*C + c)*F + f
  int f = (int)(r % F); long bc = r / F; int b = (int)(bc / C);
  float4v x;
  if (BF){
    short4v u = *(const short4v*)((const unsigned short*)Xv + e);
    x = (float4v){ bf2f((unsigned short)u[0]), bf2f((unsigned short)u[1]),
                   bf2f((unsigned short)u[2]), bf2f((unsigned short)u[3]) };
  } else {
    x = *(const float4v*)((const float*)Xv + e);
  }
  float4v iv = *(const float4v*)&invn[((long)b*F + f)*2048 + l];
  short4v o;
  #pragma unroll
  for (int j = 0; j < 4; j++){
    float v = x[j]*iv[j];
    o[j] = f2bf(SILU ? silu_g(v) : v);
  }
  *(short4v*)&XB[e] = o;
}

// ---------------- freq-pool: P[b,k,f2,l] = mean_p Hb[b,k,f2*s+p,l], bf16 ----------------
__global__ __launch_bounds__(256) void poolf_kernel(const unsigned short* __restrict__ Hb,
                                                    unsigned short* __restrict__ P,
                                                    int F2, int s, int Lc, long total4){
  long i = blockIdx.x*256 + threadIdx.x;
  if (i >= total4) return;
  long e = i*4;
  int li = (int)(e % Lc); long r0 = e / Lc;
  int f2 = (int)(r0 % F2); long r = r0 / F2;        // r = b*Kc + k
  const unsigned short* src = Hb + ((long)r*F2*s + (long)f2*s)*Lc + li;
  float a0=0,a1=0,a2=0,a3=0;
  for (int p = 0; p < s; p++){
    short4v u = *(const short4v*)(src + (long)p*Lc);
    a0 += bf2f((unsigned short)u[0]); a1 += bf2f((unsigned short)u[1]);
    a2 += bf2f((unsigned short)u[2]); a3 += bf2f((unsigned short)u[3]);
  }
  float inv = 1.f/(float)s;
  short4v o = { f2bf(a0*inv), f2bf(a1*inv), f2bf(a2*inv), f2bf(a3*inv) };
  *(short4v*)&P[((long)r*F2 + f2)*Lc + li] = o;
}

// ---------------- bf16 MFMA fused GEMM (128x128 tile, register-prefetched K-loop) ----------------
// BMODE: 0 = bf16 copy (windowed/zero-padded), 2 = audio closed-form (b0 conv1)
// EMODE: 1 bf16 store, 2 mp_add auxXH(bf16)->bf16, 3 mp_add audio-proj->bf16
struct GemmArgs {
  const unsigned short* A;       // pre-normalized bf16 weights, row-major K
  const unsigned short* Bh;      // bf16 B source
  const float* invn; const float* audio;
  const float* pw; const float* pb;
  const unsigned short* auxXH;
  unsigned short* CoutH;
  int N, K, Fdim, Lw, lq0, BLw, Bl0, CLw, Cl0, Nsto, Fsrc;
};

template<int BMODE, int EMODE>
__global__ __launch_bounds__(256,2) void mgemm_kernel(GemmArgs g){
  __shared__ __align__(16) unsigned short Asm[128*40];
  __shared__ __align__(16) unsigned short Bsm[128*40];
  const int t = threadIdx.x;
  const int lane = t & 63;
  const int wave = t >> 6;
  const int wc = wave >> 1, wsd = wave & 1;
  const int q = lane >> 4, r16 = lane & 15;
  const int s0 = blockIdx.x * 128;
  const int n0 = blockIdx.y * 128;
  const int FL = g.Fdim * g.Lw;

  // A staging mapping
  const int ar = t >> 1, ah = t & 1;
  const int an = n0 + ar;
  const bool aval = an < g.N;
  const unsigned short* Aptr = g.A + (long)an*g.K + ah*16;

  // B staging mapping: (k-group kg 0..7 of 4k, m-group mg 0..31 of 4m)
  const int kg = t & 7, mg = t >> 3;
  const int mb = s0 + mg*4;
  int bcol = mb / FL; int rr = mb - bcol*FL;
  int fcol = (g.Fdim > 1) ? (rr / g.Lw) : 0;
  int labs = g.lq0 + (rr - fcol*g.Lw);
  const bool cv = (bcol < 2);
  bool lv[4];
  #pragma unroll
  for (int j = 0; j < 4; j++) lv[j] = cv && (labs + j >= 0) && (labs + j < 2048);
  const bool vec4 = cv && (labs >= 0) && (labs + 3 < 2048);
  const unsigned short* bbase = g.Bh;
  if (cv) bbase = g.Bh + ((long)(bcol*g.K)*g.Fsrc + fcol)*g.BLw + (labs - g.Bl0);
  const long kstep = (long)g.Fsrc * g.BLw;

  float invn4[4] = {0,0,0,0}, aud4[4] = {0,0,0,0};
  if (BMODE == 2){
    #pragma unroll
    for (int j = 0; j < 4; j++) if (lv[j]){
      invn4[j] = g.invn[(bcol*g.Fdim + fcol)*2048 + labs + j];
      aud4[j]  = g.audio[(bcol*128 + fcol)*2048 + labs + j];
    }
  }

  float4v acc[4][4];
  #pragma unroll
  for (int i = 0; i < 4; i++)
    #pragma unroll
    for (int j = 0; j < 4; j++) acc[i][j] = (float4v){0.f,0.f,0.f,0.f};

  // prefetch registers
  short8 pa0 = {0,0,0,0,0,0,0,0}, pa1 = {0,0,0,0,0,0,0,0};
  short4v praw[4];
  #pragma unroll
  for (int i = 0; i < 4; i++) praw[i] = (short4v){0,0,0,0};

  auto ldA = [&](int kb){
    if (aval){
      pa0 = *(const short8*)(Aptr + kb);
      pa1 = *(const short8*)(Aptr + kb + 8);
    }
  };
  auto ldB = [&](int kb){
    #pragma unroll
    for (int i = 0; i < 4; i++){
      const int k = kb + kg*4 + i;
      const unsigned short* bp = bbase + (long)k*kstep;
      if (vec4) praw[i] = *(const short4v*)bp;
      else {
        short4v u = {0,0,0,0};
        #pragma unroll
        for (int j = 0; j < 4; j++) if (lv[j]) u[j] = (short)bp[j];
        praw[i] = u;
      }
    }
  };

  ldA(0);
  if (BMODE == 0) ldB(0);

  for (int k0 = 0; k0 < g.K; k0 += 32){
    short8 sa0 = pa0, sa1 = pa1;
    short4v bpk[4];
    if (BMODE == 0){
      #pragma unroll
      for (int j = 0; j < 4; j++){
        short4v p;
        #pragma unroll
        for (int i = 0; i < 4; i++) p[i] = praw[i][j];
        bpk[j] = p;
      }
    } else { // BMODE == 2
      float tv[4][4];
      #pragma unroll
      for (int i = 0; i < 4; i++){
        const int k = k0 + kg*4 + i;
        const float pwk = g.pw[k], pbk = g.pb[k];
        #pragma unroll
        for (int j = 0; j < 4; j++) tv[i][j] = lv[j] ? silu_g((aud4[j]*pwk + pbk)*invn4[j]) : 0.f;
      }
      #pragma unroll
      for (int j = 0; j < 4; j++){
        short4v p;
        #pragma unroll
        for (int i = 0; i < 4; i++) p[i] = f2bf(tv[i][j]);
        bpk[j] = p;
      }
    }
    if (k0 + 32 < g.K){
      ldA(k0 + 32);
      if (BMODE == 0) ldB(k0 + 32);
    }

    __syncthreads();
    *(short8*)&Asm[ar*40 + ah*16]     = sa0;
    *(short8*)&Asm[ar*40 + ah*16 + 8] = sa1;
    #pragma unroll
    for (int j = 0; j < 4; j++)
      *(short4v*)&Bsm[(mg*4 + j)*40 + kg*4] = bpk[j];
    __syncthreads();

    short8 afr[4], bfr[4];
    #pragma unroll
    for (int i = 0; i < 4; i++) afr[i] = *(const short8*)&Asm[(wc*64 + i*16 + r16)*40 + q*8];
    #pragma unroll
    for (int j = 0; j < 4; j++) bfr[j] = *(const short8*)&Bsm[(wsd*64 + j*16 + r16)*40 + q*8];
    #pragma unroll
    for (int i = 0; i < 4; i++)
      #pragma unroll
      for (int j = 0; j < 4; j++)
        acc[i][j] = __builtin_amdgcn_mfma_f32_16x16x32_bf16(afr[i], bfr[j], acc[i][j], 0, 0, 0);
  }

  // ---- epilogue ----
  #pragma unroll
  for (int j = 0; j < 4; j++){
    int sg = s0 + wsd*64 + j*16 + r16;
    int b2 = sg / FL; int r2 = sg - b2*FL;
    int f2 = (g.Fdim > 1) ? (r2 / g.Lw) : 0;
    int l2 = g.lq0 + (r2 - f2*g.Lw);
    if (b2 >= 2 || l2 < 0 || l2 >= 2048) continue;
    float invn_p = 0.f, aud_p = 0.f;
    if (EMODE==2 || EMODE==3) invn_p = g.invn[(b2*g.Fdim + f2)*2048 + l2];
    if (EMODE==3) aud_p = g.audio[(b2*128 + f2)*2048 + l2];
    #pragma unroll
    for (int i = 0; i < 4; i++){
      #pragma unroll
      for (int rg = 0; rg < 4; rg++){
        int n = n0 + wc*64 + i*16 + q*4 + rg;
        if (n >= g.N) continue;
        float v = acc[i][j][rg];
        long oidx = ((long)(b2*g.Nsto + n)*g.Fdim + f2)*g.CLw + (l2 - g.Cl0);
        if (EMODE == 1){
          g.CoutH[oidx] = (unsigned short)f2bf(v);
        } else if (EMODE == 2){
          float xn = bf2f(g.auxXH[((long)(b2*g.N + n)*g.Fdim + f2)*2048 + l2]) * invn_p;
          g.CoutH[oidx] = (unsigned short)f2bf((xn*0.7f + v*0.3f)*MPS);
        } else if (EMODE == 3){
          float xn = (aud_p*g.pw[n] + g.pb[n])*invn_p;
          g.CoutH[oidx] = (unsigned short)f2bf((xn*0.7f + v*0.3f)*MPS);
        }
      }
    }
  }
}

// ---------------- downsample conv GEMM: 64x64 tile on pooled P, prefetched ----------------
// EMODE 0: f32 store full-L ; EMODE 1: bf16 store full-L
struct DnArgs {
  const unsigned short* A; const unsigned short* P;
  float* Cout; unsigned short* CoutH;
  int N, K, F2, Lc, l0;
};

template<int EMODE>
__global__ __launch_bounds__(256,4) void mgemm64_kernel(DnArgs g){
  __shared__ __align__(16) unsigned short Asm[64*40];
  __shared__ __align__(16) unsigned short Bsm[64*40];
  const int t = threadIdx.x;
  const int lane = t & 63;
  const int wave = t >> 6;
  const int wc = wave >> 1, wsd = wave & 1;
  const int q = lane >> 4, r16 = lane & 15;
  const int s0 = blockIdx.x * 64;
  const int n0 = blockIdx.y * 64;
  const int FL = g.F2 * g.Lc;

  const int ar = t >> 2, ah = t & 3;
  const unsigned short* Aptr = g.A + (long)(n0 + ar)*g.K + ah*8;
  const int kg = t & 7, mg = t >> 3;
  const bool bstage = (mg < 16);
  const int mb = s0 + (mg & 15)*4;
  const int bcol = mb / FL; const int rr = mb - bcol*FL;
  const int fcol = rr / g.Lc; const int li = rr - fcol*g.Lc;
  const unsigned short* bbase = g.P + ((long)(bcol*g.K)*g.F2 + fcol)*g.Lc + li;
  const long kstep = (long)g.F2 * g.Lc;

  float4v acc[2][2];
  #pragma unroll
  for (int i = 0; i < 2; i++)
    #pragma unroll
    for (int j = 0; j < 2; j++) acc[i][j] = (float4v){0.f,0.f,0.f,0.f};

  short8 pa = {0,0,0,0,0,0,0,0};
  short4v praw[4];
  #pragma unroll
  for (int i = 0; i < 4; i++) praw[i] = (short4v){0,0,0,0};

  auto ldA = [&](int kb){ pa = *(const short8*)(Aptr + kb); };
  auto ldB = [&](int kb){
    if (bstage){
      #pragma unroll
      for (int i = 0; i < 4; i++)
        praw[i] = *(const short4v*)(bbase + (long)(kb + kg*4 + i)*kstep);
    }
  };
  ldA(0); ldB(0);

  for (int k0 = 0; k0 < g.K; k0 += 32){
    short8 sa = pa;
    short4v bpk[4];
    #pragma unroll
    for (int j = 0; j < 4; j++){
      short4v p;
      #pragma unroll
      for (int i = 0; i < 4; i++) p[i] = praw[i][j];
      bpk[j] = p;
    }
    if (k0 + 32 < g.K){ ldA(k0 + 32); ldB(k0 + 32); }

    __syncthreads();
    *(short8*)&Asm[ar*40 + ah*8] = sa;
    if (bstage){
      #pragma unroll
      for (int j = 0; j < 4; j++)
        *(short4v*)&Bsm[((mg & 15)*4 + j)*40 + kg*4] = bpk[j];
    }
    __syncthreads();

    short8 afr[2], bfr[2];
    #pragma unroll
    for (int i = 0; i < 2; i++) afr[i] = *(const short8*)&Asm[(wc*32 + i*16 + r16)*40 + q*8];
    #pragma unroll
    for (int j = 0; j < 2; j++) bfr[j] = *(const short8*)&Bsm[(wsd*32 + j*16 + r16)*40 + q*8];
    #pragma unroll
    for (int i = 0; i < 2; i++)
      #pragma unroll
      for (int j = 0; j < 2; j++)
        acc[i][j] = __builtin_amdgcn_mfma_f32_16x16x32_bf16(afr[i], bfr[j], acc[i][j], 0, 0, 0);
  }

  #pragma unroll
  for (int j = 0; j < 2; j++){
    int sg = s0 + wsd*32 + j*16 + r16;
    int b2 = sg / FL; int r2 = sg - b2*FL;
    int f2 = r2 / g.Lc; int l2 = g.l0 + (r2 - f2*g.Lc);
    #pragma unroll
    for (int i = 0; i < 2; i++){
      #pragma unroll
      for (int rg = 0; rg < 4; rg++){
        int n = n0 + wc*32 + i*16 + q*4 + rg;
        float v = acc[i][j][rg];
        long oidx = ((long)(b2*g.N + n)*g.F2 + f2)*2048 + l2;
        if (EMODE == 0) g.Cout[oidx] = v;
        else            g.CoutH[oidx] = (unsigned short)f2bf(v);
      }
    }
  }
}

// ---------------- seq GEMM: 128M x 64N tile, Fdim=1, prefetched ----------------
// EMODE 1: bf16 store; EMODE 4: split n<Nsto silu->CoutH else raw->Cout2H
struct SmArgs {
  const unsigned short* A; const unsigned short* Bh;
  unsigned short* CoutH; unsigned short* Cout2H;
  int K, Nsto;
};

template<int EMODE>
__global__ __launch_bounds__(256,4) void seqMN_kernel(SmArgs g){
  __shared__ __align__(16) unsigned short Asm[64*40];
  __shared__ __align__(16) unsigned short Bsm[128*40];
  const int t = threadIdx.x;
  const int lane = t & 63;
  const int wave = t >> 6;
  const int wc = wave >> 1, wsd = wave & 1;   // wc: N half (2x32), wsd: M half (2x64)
  const int q = lane >> 4, r16 = lane & 15;
  const int s0 = blockIdx.x * 128;
  const int n0 = blockIdx.y * 64;
  const int K = g.K;

  // A staging: 64 rows x 32 k, 8 shorts/thread
  const int ar = t >> 2, ah = t & 3;
  const unsigned short* Aptr = g.A + (long)(n0 + ar)*K + ah*8;
  // B staging: mg 0..31 (4 m each), kg 0..7 (4 k each)
  const int kg = t & 7, mg = t >> 3;
  const int mb = s0 + mg*4;
  const int bcol = mb >> 11, lb = mb & 2047;
  const unsigned short* bbase = g.Bh + ((long)bcol*K)*2048 + lb;

  float4v acc[2][4];
  #pragma unroll
  for (int i = 0; i < 2; i++)
    #pragma unroll
    for (int j = 0; j < 4; j++) acc[i][j] = (float4v){0.f,0.f,0.f,0.f};

  short8 pa = {0,0,0,0,0,0,0,0};
  short4v praw[4];
  #pragma unroll
  for (int i = 0; i < 4; i++) praw[i] = (short4v){0,0,0,0};

  auto ldA = [&](int kb){ pa = *(const short8*)(Aptr + kb); };
  auto ldB = [&](int kb){
    #pragma unroll
    for (int i = 0; i < 4; i++)
      praw[i] = *(const short4v*)(bbase + (long)(kb + kg*4 + i)*2048);
  };
  ldA(0); ldB(0);

  for (int k0 = 0; k0 < K; k0 += 32){
    short8 sa = pa;
    short4v bpk[4];
    #pragma unroll
    for (int j = 0; j < 4; j++){
      short4v p;
      #pragma unroll
      for (int i = 0; i < 4; i++) p[i] = praw[i][j];
      bpk[j] = p;
    }
    if (k0 + 32 < K){ ldA(k0 + 32); ldB(k0 + 32); }

    __syncthreads();
    *(short8*)&Asm[ar*40 + ah*8] = sa;
    #pragma unroll
    for (int j = 0; j < 4; j++)
      *(short4v*)&Bsm[(mg*4 + j)*40 + kg*4] = bpk[j];
    __syncthreads();

    short8 afr[2], bfr[4];
    #pragma unroll
    for (int i = 0; i < 2; i++) afr[i] = *(const short8*)&Asm[(wc*32 + i*16 + r16)*40 + q*8];
    #pragma unroll
    for (int j = 0; j < 4; j++) bfr[j] = *(const short8*)&Bsm[(wsd*64 + j*16 + r16)*40 + q*8];
    #pragma unroll
    for (int i = 0; i < 2; i++)
      #pragma unroll
      for (int j = 0; j < 4; j++)
        acc[i][j] = __builtin_amdgcn_mfma_f32_16x16x32_bf16(afr[i], bfr[j], acc[i][j], 0, 0, 0);
  }

  #pragma unroll
  for (int j = 0; j < 4; j++){
    int sg = s0 + wsd*64 + j*16 + r16;
    int b2 = sg >> 11, l2 = sg & 2047;
    #pragma unroll
    for (int i = 0; i < 2; i++){
      #pragma unroll
      for (int rg = 0; rg < 4; rg++){
        int n = n0 + wc*32 + i*16 + q*4 + rg;
        float v = acc[i][j][rg];
        if (EMODE == 1){
          g.CoutH[((long)(b2*g.Nsto + n))*2048 + l2] = (unsigned short)f2bf(v);
        } else { // EMODE == 4
          if (n < g.Nsto) g.CoutH[((long)(b2*g.Nsto + n))*2048 + l2] = (unsigned short)f2bf(silu_g(v));
          else            g.Cout2H[((long)(b2*g.Nsto + (n - g.Nsto)))*2048 + l2] = (unsigned short)f2bf(v);
        }
      }
    }
  }
}

// ---------------- seq out GEMM: 64x64 tile, Fdim=1, prefetched ----------------
// EMODE 5: mp_add auxX -> f32; EMODE 6: mp_add + silu -> f32
struct SqArgs {
  const unsigned short* A; const unsigned short* Bh;
  const float* invn; const float* auxX;
  float* Cout;
  int K, Nsto;
};

template<int EMODE>
__global__ __launch_bounds__(256,4) void seq64_kernel(SqArgs g){
  __shared__ __align__(16) unsigned short Asm[64*40];
  __shared__ __align__(16) unsigned short Bsm[64*40];
  const int t = threadIdx.x;
  const int lane = t & 63;
  const int wave = t >> 6;
  const int wc = wave >> 1, wsd = wave & 1;
  const int q = lane >> 4, r16 = lane & 15;
  const int s0 = blockIdx.x * 64;
  const int n0 = blockIdx.y * 64;
  const int K = g.K;

  const int ar = t >> 2, ah = t & 3;
  const unsigned short* Aptr = g.A + (long)(n0 + ar)*K + ah*8;
  const int kg = t & 7, mg = t >> 3;
  const bool bstage = (mg < 16);
  const int mb = s0 + (mg & 15)*4;
  const int bcol = mb >> 11, lb = mb & 2047;
  const unsigned short* bbase = g.Bh + ((long)bcol*K)*2048 + lb;

  float4v acc[2][2];
  #pragma unroll
  for (int i = 0; i < 2; i++)
    #pragma unroll
    for (int j = 0; j < 2; j++) acc[i][j] = (float4v){0.f,0.f,0.f,0.f};

  short8 pa = {0,0,0,0,0,0,0,0};
  short4v praw[4];
  #pragma unroll
  for (int i = 0; i < 4; i++) praw[i] = (short4v){0,0,0,0};

  auto ldA = [&](int kb){ pa = *(const short8*)(Aptr + kb); };
  auto ldB = [&](int kb){
    if (bstage){
      #pragma unroll
      for (int i = 0; i < 4; i++)
        praw[i] = *(const short4v*)(bbase + (long)(kb + kg*4 + i)*2048);
    }
  };
  ldA(0); ldB(0);

  for (int k0 = 0; k0 < K; k0 += 32){
    short8 sa = pa;
    short4v bpk[4];
    #pragma unroll
    for (int j = 0; j < 4; j++){
      short4v p;
      #pragma unroll
      for (int i = 0; i < 4; i++) p[i] = praw[i][j];
      bpk[j] = p;
    }
    if (k0 + 32 < K){ ldA(k0 + 32); ldB(k0 + 32); }

    __syncthreads();
    *(short8*)&Asm[ar*40 + ah*8] = sa;
    if (bstage){
      #pragma unroll
      for (int j = 0; j < 4; j++)
        *(short4v*)&Bsm[((mg & 15)*4 + j)*40 + kg*4] = bpk[j];
    }
    __syncthreads();

    short8 afr[2], bfr[2];
    #pragma unroll
    for (int i = 0; i < 2; i++) afr[i] = *(const short8*)&Asm[(wc*32 + i*16 + r16)*40 + q*8];
    #pragma unroll
    for (int j = 0; j < 2; j++) bfr[j] = *(const short8*)&Bsm[(wsd*32 + j*16 + r16)*40 + q*8];
    #pragma unroll
    for (int i = 0; i < 2; i++)
      #pragma unroll
      for (int j = 0; j < 2; j++)
        acc[i][j] = __builtin_amdgcn_mfma_f32_16x16x32_bf16(afr[i], bfr[j], acc[i][j], 0, 0, 0);
  }

  #pragma unroll
  for (int j = 0; j < 2; j++){
    int sg = s0 + wsd*32 + j*16 + r16;
    int b2 = sg >> 11, l2 = sg & 2047;
    float invn_p = g.invn[b2*2048 + l2];
    #pragma unroll
    for (int i = 0; i < 2; i++){
      #pragma unroll
      for (int rg = 0; rg < 4; rg++){
        int n = n0 + wc*32 + i*16 + q*4 + rg;
        float v = acc[i][j][rg];
        float xn = g.auxX[((long)b2*512 + n)*2048 + l2] * invn_p;
        float r = (xn*0.7f + v*0.3f)*MPS;
        if (EMODE == 6) r = silu_g(r);
        g.Cout[((long)b2*512 + n)*2048 + l2] = r;
      }
    }
  }
}

// ---------------- depthwise 5x3 conv (+ silu), bf16 in/out ----------------
// 4 f-rows x 8 l per thread; each input row loaded once, feeds up to 3 f-accumulators
struct DwArgs { const unsigned short* R1; const unsigned short* wd; unsigned short* R2; int C, F, Lc, l0; };
__global__ __launch_bounds__(256) void dw2d_kernel(DwArgs a){
  int idx = blockIdx.x*256 + threadIdx.x;
  int Lq = a.Lc >> 3;
  int Fq = a.F >> 2;
  int total = 2*a.C*Fq*Lq;
  if (idx >= total) return;
  int lq = idx % Lq; int r = idx / Lq;
  int fq = r % Fq; r /= Fq;
  int c = r % a.C; int b = r / a.C;
  int f0 = fq*4;
  int labs = a.l0 + lq*8;
  int Lw = a.Lc + 8;
  const unsigned short* base = a.R1 + (long)((b*a.C + c)*a.F)*Lw + (labs - (a.l0 - 4));
  const unsigned short* w = a.wd + c*15;
  float W[5][3];
  #pragma unroll
  for (int tp = 0; tp < 5; tp++)
    #pragma unroll
    for (int j = 0; j < 3; j++) W[tp][j] = bf2f(w[tp*3 + j]);

  const bool llo = (labs > 0);
  const bool lhi = (labs + 8 < 2048);
  float acc[4][8];
  #pragma unroll
  for (int t = 0; t < 4; t++)
    #pragma unroll
    for (int j = 0; j < 8; j++) acc[t][j] = 0.f;

  #pragma unroll
  for (int r8 = 0; r8 < 8; r8++){
    int rrow = f0 - 2 + r8;
    if (rrow < 0 || rrow >= a.F) continue;
    const unsigned short* p = base + (long)rrow*Lw;
    short4v u0 = *(const short4v*)p;
    short4v u1 = *(const short4v*)(p + 4);
    float x[10];
    x[0] = llo ? bf2f(p[-1]) : 0.f;
    x[1] = bf2f((unsigned short)u0[0]); x[2] = bf2f((unsigned short)u0[1]);
    x[3] = bf2f((unsigned short)u0[2]); x[4] = bf2f((unsigned short)u0[3]);
    x[5] = bf2f((unsigned short)u1[0]); x[6] = bf2f((unsigned short)u1[1]);
    x[7] = bf2f((unsigned short)u1[2]); x[8] = bf2f((unsigned short)u1[3]);
    x[9] = lhi ? bf2f(p[8]) : 0.f;
    #pragma unroll
    for (int t = 0; t < 4; t++){
      const int df = r8 - 2 - t;
      if (df < -2 || df > 2) continue;
      float w0 = W[df+2][0], w1 = W[df+2][1], w2 = W[df+2][2];
      #pragma unroll
      for (int j = 0; j < 8; j++)
        acc[t][j] += w0*x[j] + w1*x[j+1] + w2*x[j+2];
    }
  }

  unsigned short* ob = a.R2 + ((long)((b*a.C + c)*a.F + f0))*a.Lc + (labs - a.l0);
  #pragma unroll
  for (int t = 0; t < 4; t++){
    short8 o;
    #pragma unroll
    for (int j = 0; j < 8; j++) o[j] = f2bf(silu_g(acc[t][j]));
    *(short8*)(ob + (long)t*a.Lc) = o;
  }
}

// ---------------- seq depthwise 3-tap (+ silu), bf16 in/out ----------------
__global__ __launch_bounds__(256) void dwseq_kernel(const unsigned short* __restrict__ HS, const unsigned short* __restrict__ w,
                                                    unsigned short* __restrict__ H2){
  int idx = blockIdx.x*256 + threadIdx.x;
  if (idx >= 2*1024*512) return;
  int e = idx*4;
  int tt = e & 2047; int bc = e >> 11; int c = bc & 1023;
  const unsigned short* base = HS + (long)bc*2048 + tt;
  float w0 = bf2f(w[c*3+0]), w1 = bf2f(w[c*3+1]), w2 = bf2f(w[c*3+2]);
  short4v u = *(const short4v*)base;
  float xm = (tt > 0) ? bf2f(base[-1]) : 0.f;
  float x0 = bf2f((unsigned short)u[0]), x1 = bf2f((unsigned short)u[1]);
  float x2 = bf2f((unsigned short)u[2]), x3 = bf2f((unsigned short)u[3]);
  float x4 = (tt < 2044) ? bf2f(base[4]) : 0.f;
  short4v o = { f2bf(silu_g(w0*xm + w1*x0 + w2*x1)),
                f2bf(silu_g(w0*x0 + w1*x1 + w2*x2)),
                f2bf(silu_g(w0*x1 + w1*x2 + w2*x3)),
                f2bf(silu_g(w0*x2 + w1*x3 + w2*x4)) };
  *(short4v*)&H2[(long)bc*2048 + tt] = o;
}

// ---------------- minGRU scan + gate (bf16 z/c) ----------------
__global__ __launch_bounds__(256) void scan_kernel(const unsigned short* __restrict__ ZC, const unsigned short* __restrict__ G,
                                                   unsigned short* __restrict__ SC){
  int bc = blockIdx.x;            // 0..2047 = b*1024+c
  int b = bc >> 10, c = bc & 1023;
  const unsigned short* zrow = ZC + ((long)(b*2048 + c))*2048;
  const unsigned short* crow = ZC + ((long)(b*2048 + 1024 + c))*2048;
  const unsigned short* grow = G + (long)bc*2048;
  unsigned short* orow = SC + (long)bc*2048;
  int tid = threadIdx.x;
  int t0 = tid*8;
  short8 zv = *(const short8*)&zrow[t0];
  short8 cv = *(const short8*)&crow[t0];
  float av[8], bv[8];
  float A = 1.f, Bv = 0.f;
  #pragma unroll
  for (int j = 0; j < 8; j++){
    float z = bf2f((unsigned short)zv[j]); float cval = bf2f((unsigned short)cv[j]);
    float zs = 1.f/(1.f + __expf(-z));
    float a = 1.f - zs; float bb = zs*cval;
    av[j] = a; bv[j] = bb;
    Bv = a*Bv + bb;
    A = a*A;
  }
  __shared__ float sA[256], sB[256];
  sA[tid] = A; sB[tid] = Bv;
  __syncthreads();
  for (int off = 1; off < 256; off <<= 1){
    float pA = 1.f, pB = 0.f;
    if (tid >= off){ pA = sA[tid-off]; pB = sB[tid-off]; }
    __syncthreads();
    float nA = A*pA; float nB = A*pB + Bv;
    A = nA; Bv = nB;
    sA[tid] = A; sB[tid] = Bv;
    __syncthreads();
  }
  float h = (tid > 0) ? sB[tid-1] : 0.f;
  short8 gv = *(const short8*)&grow[t0];
  short8 ov;
  #pragma unroll
  for (int j = 0; j < 8; j++){
    h = av[j]*h + bv[j];
    ov[j] = f2bf(h * silu_g(bf2f((unsigned short)gv[j])));
  }
  *(short8*)&orow[t0] = ov;
}

extern "C" void kernel_launch(void* const* d_in, const int* in_sizes, int n_in,
                              void* d_out, int out_size, void* d_ws, size_t ws_size,
                              hipStream_t stream) {
  const float* audio = (const float*)d_in[0];
  const float* pw = (const float*)d_in[1];
  const float* pb = (const float*)d_in[2];
  const float* cw1[3] = {(const float*)d_in[3], (const float*)d_in[7], (const float*)d_in[11]};
  const float* cwd[3] = {(const float*)d_in[4], (const float*)d_in[8], (const float*)d_in[12]};
  const float* cw2[3] = {(const float*)d_in[5], (const float*)d_in[9], (const float*)d_in[13]};
  const float* cdn[3] = {(const float*)d_in[6], (const float*)d_in[10], (const float*)d_in[14]};
  const float* hgw  = (const float*)d_in[15];
  const float* dww  = (const float*)d_in[16];
  const float* gruw = (const float*)d_in[17];
  const float* outw = (const float*)d_in[18];
  float* out = (float*)d_out;

  // ---- workspace layout (bytes) ----
  char* P0 = (char*)d_ws;
  float*          INVW = (float*)P0;                    P0 += 131072;     // 25664 used + S at [32000]
  unsigned short* WBF  = (unsigned short*)P0;           P0 += 30443776;   // 15,221,888 bf16
  float*          INVN = (float*)P0;                    P0 += 2097152;
  char*           XBZC = P0;                            P0 += 33554432;   // XB (conv b1/b2) / ZC bf16 (seq)
  unsigned short* IN1h = (unsigned short*)P0;           P0 += 33554432;   // b0 out bf16; seq scratch later
  unsigned short* IN2h = (unsigned short*)P0;           P0 += 16777216;   // b1 out bf16
  float*          SEQ  = (float*)P0;                    P0 += 8388608;    // b2 out fp32
  char*           ARENA = P0;
  long arenaBytes = (long)ws_size - (long)(P0 - (char*)d_ws);
  float* S = INVW + 32000;

  // weight table (order: cw1/cwd/cw2/cdn x3, hg, dww, gru, out)
  const float* wsrc[16] = {cw1[0],cwd[0],cw2[0],cdn[0], cw1[1],cwd[1],cw2[1],cdn[1],
                           cw1[2],cwd[2],cw2[2],cdn[2], hgw, dww, gruw, outw};
  int Os[16] = {128,128,64,128, 256,256,128,256, 512,512,256,512, 8192,4096,8192,2048};
  int Ks[16] = {64,15,128,64, 128,15,256,128, 256,15,512,256, 512,3,1024,1024};
  int wbfOff[16], ivOff[16];
  {
    int wo = 0, io = 0;
    for (int i = 0; i < 16; i++){ wbfOff[i] = wo; ivOff[i] = io; wo += Os[i]*Ks[i]; io += Os[i]; }
  }
  {
    NormArgs na;
    int rows = 0;
    for (int i = 0; i < 16; i++){ na.e[i].w = wsrc[i]; na.e[i].O = Os[i]; na.e[i].K = Ks[i]; na.e[i].off = ivOff[i]; rows += Os[i]; }
    rownorm_kernel<<<rows, 64, 0, stream>>>(na, INVW);
  }
  {
    WcArgs wa; int base = 0;
    for (int i = 0; i < 16; i++){
      wa.e[i].src = wsrc[i]; wa.e[i].dstOff = wbfOff[i]; wa.e[i].K = Ks[i];
      wa.e[i].invwOff = ivOff[i]; wa.e[i].base = base; base += Os[i]*Ks[i];
    }
    wa.total = base;
    wcast_kernel<<<(base+255)/256, 256, 0, stream>>>(wa, INVW, WBF);
  }
  projstats_kernel<<<1, 64, 0, stream>>>(pw, pb, S);

  // ---- conv blocks ----
  int Cin_[3]  = {64,128,256};
  int Cmid_[3] = {128,256,512};
  int F_[3]    = {128,32,8};
  int s_[3]    = {4,4,8};
  const unsigned short* XinH[3] = {nullptr, IN1h, IN2h};
  unsigned short* XoutH[3] = {IN1h, IN2h, nullptr};
  int iW1[3]={0,4,8}, iWd[3]={1,5,9}, iW2[3]={2,6,10}, iDn[3]={3,7,11};

  for (int b = 0; b < 3; b++){
    int Cin = Cin_[b], Cmid = Cmid_[b], F = F_[b], s = s_[b];
    int F2 = F/s;
    int nc = 16;
    for (int c = 1; c <= 16; c <<= 1){
      long Lc = 2048/c;
      long bytes = 2L*(2L*Cmid*F*(Lc+8) + 2L*Cmid*F*Lc + 2L*Cin*F*Lc + 2L*Cin*F2*Lc);
      if (bytes <= arenaBytes){ nc = c; break; }
    }
    int Lc = 2048/nc;
    unsigned short* R1 = (unsigned short*)ARENA;
    unsigned short* R2 = R1 + 2L*Cmid*F*(Lc+8);
    unsigned short* Hb = R2 + 2L*Cmid*F*Lc;
    unsigned short* Pb = Hb + 2L*Cin*F*Lc;
    unsigned short* XB = (unsigned short*)XBZC;

    if (b == 0){
      invn_audio_kernel<<<(2*128*2048/4+255)/256, 256, 0, stream>>>(audio, S, INVN);
    } else {
      int positions = 2*F*2048;
      invn_reduce_kernel<8,true><<<positions/32, 256, 0, stream>>>(XinH[b], INVN, Cin, F);
      long total4 = (long)2*Cin*F*2048/4;
      applynorm_kernel<true,true><<<(int)((total4+255)/256), 256, 0, stream>>>(XinH[b], INVN, XB, Cin, F, total4);
    }

    for (int ci = 0; ci < nc; ci++){
      int l0 = ci*Lc;
      // conv1: Cin -> Cmid on window [l0-4, l0+Lc+4) -> R1 bf16
      GemmArgs ga{};
      ga.A = WBF + wbfOff[iW1[b]];
      ga.Bh = XB; ga.invn = INVN; ga.audio = audio; ga.pw = pw; ga.pb = pb;
      ga.CoutH = R1; ga.N = Cmid; ga.K = Cin; ga.Fdim = F; ga.Lw = Lc+8; ga.lq0 = l0-4;
      ga.BLw = 2048; ga.Bl0 = 0; ga.CLw = Lc+8; ga.Cl0 = l0-4; ga.Nsto = Cmid; ga.Fsrc = F;
      int M1 = 2*F*(Lc+8);
      dim3 g1((M1+127)/128, (Cmid+127)/128);
      if (b == 0) mgemm_kernel<2,1><<<g1,256,0,stream>>>(ga);
      else        mgemm_kernel<0,1><<<g1,256,0,stream>>>(ga);
      // depthwise 5x3 + silu -> R2 bf16 (4f x 8l per thread)
      DwArgs da{R1, WBF + wbfOff[iWd[b]], R2, Cmid, F, Lc, l0};
      int tdw = 2*Cmid*(F/4)*(Lc/8);
      dw2d_kernel<<<(tdw+255)/256, 256, 0, stream>>>(da);
      // conv2 + mp_add -> Hb bf16
      GemmArgs gb{};
      gb.A = WBF + wbfOff[iW2[b]];
      gb.Bh = R2; gb.invn = INVN; gb.audio = audio; gb.pw = pw; gb.pb = pb; gb.auxXH = XinH[b];
      gb.CoutH = Hb; gb.N = Cin; gb.K = Cmid; gb.Fdim = F; gb.Lw = Lc; gb.lq0 = l0;
      gb.BLw = Lc; gb.Bl0 = l0; gb.CLw = Lc; gb.Cl0 = l0; gb.Nsto = Cin; gb.Fsrc = F;
      int M2 = 2*F*Lc;
      dim3 g2((M2+127)/128, (Cin+127)/128);
      if (b == 0) mgemm_kernel<0,3><<<g2,256,0,stream>>>(gb);
      else        mgemm_kernel<0,2><<<g2,256,0,stream>>>(gb);
      // freq-pool Hb -> Pb (bf16)
      long tp4 = (2L*Cin*F2*Lc)/4;
      poolf_kernel<<<(int)((tp4+255)/256), 256, 0, stream>>>(Hb, Pb, F2, s, Lc, tp4);
      // dn conv on pooled P -> Xout (bf16 full-L for b0/b1; fp32 SEQ for b2)
      DnArgs dn{};
      dn.A = WBF + wbfOff[iDn[b]]; dn.P = Pb;
      dn.Cout = SEQ; dn.CoutH = XoutH[b];
      dn.N = Cmid; dn.K = Cin; dn.F2 = F2; dn.Lc = Lc; dn.l0 = l0;
      dim3 gdn((2*F2*Lc)/64, Cmid/64);
      if (b == 2) mgemm64_kernel<0><<<gdn,256,0,stream>>>(dn);
      else        mgemm64_kernel<1><<<gdn,256,0,stream>>>(dn);
    }
  }

  // ---- seq blocks (bf16 scratch spans IN1h+IN2h; ZC bf16 in XBZC) ----
  unsigned short* XS = IN1h;
  unsigned short* HS = XS + 2097152;
  unsigned short* G  = HS + 4194304;
  unsigned short* H2 = G  + 4194304;
  unsigned short* SC = H2 + 4194304;
  unsigned short* ZCh = (unsigned short*)XBZC;

  for (int i = 0; i < 4; i++){
    invn_reduce_kernel<16,false><<<4096/16, 256, 0, stream>>>(SEQ, INVN, 512, 1);
    applynorm_kernel<false,false><<<(2*512*2048/4)/256, 256, 0, stream>>>(SEQ, INVN, XS, 512, 1, (long)2*512*2048/4);
    // hg conv (both halves): n<1024 -> silu -> HS, else raw -> G (1024 blocks, 128Mx64N)
    SmArgs gh{};
    gh.A = WBF + wbfOff[12] + (long)i*2048*512;
    gh.Bh = XS; gh.CoutH = HS; gh.Cout2H = G;
    gh.K = 512; gh.Nsto = 1024;
    seqMN_kernel<4><<<dim3(32,32),256,0,stream>>>(gh);
    // depthwise 3-tap + silu
    dwseq_kernel<<<(2*1024*512)/256, 256, 0, stream>>>(HS, WBF + wbfOff[13] + i*1024*3, H2);
    // gru conv 1024 -> 2048 (z|c) -> ZCh bf16 (1024 blocks, 128Mx64N)
    SmArgs gz{};
    gz.A = WBF + wbfOff[14] + (long)i*2048*1024;
    gz.Bh = H2; gz.CoutH = ZCh;
    gz.K = 1024; gz.Nsto = 2048;
    seqMN_kernel<1><<<dim3(32,32),256,0,stream>>>(gz);
    // scan + gate -> SC bf16
    scan_kernel<<<2048,256,0,stream>>>(ZCh, G, SC);
    // out conv + mp_add -> SEQ (i<3) or mp_add+silu -> d_out (i==3)
    SqArgs go{};
    go.A = WBF + wbfOff[15] + (long)i*512*1024;
    go.Bh = SC; go.invn = INVN; go.auxX = SEQ;
    go.K = 1024; go.Nsto = 512;
    if (i < 3){ go.Cout = SEQ; seq64_kernel<5><<<dim3(64,8),256,0,stream>>>(go); }
    else      { go.Cout = out; seq64_kernel<6><<<dim3(64,8),256,0,stream>>>(go); }
  }

  (void)in_sizes; (void)n_in; (void)out_size;
}